// Round 1
// baseline (620.893 us; speedup 1.0000x reference)
//
#include <hip/hip_runtime.h>

#define D 128
#define SB 256

// ---------------- CSR build ----------------

__global__ void k_init(int* __restrict__ cnt, int* __restrict__ cursor, int n) {
    int i = blockIdx.x * blockDim.x + threadIdx.x;
    if (i < n) { cnt[i] = 0; cursor[i] = 0; }
}

__global__ void k_count(const int* __restrict__ dst, int* __restrict__ cnt, int E) {
    int e = blockIdx.x * blockDim.x + threadIdx.x;
    if (e < E) atomicAdd(&cnt[dst[e]], 1);
}

__global__ void k_dinv(const int* __restrict__ cnt, float* __restrict__ dinv, int n) {
    int i = blockIdx.x * blockDim.x + threadIdx.x;
    if (i < n) dinv[i] = rsqrtf((float)cnt[i] + 1.0f);  // +1 self-loop; deg >= 1 always
}

// inclusive scan within 256-blocks; rp[i+1] = local inclusive, bsum[b] = block total
__global__ void k_scan1(const int* __restrict__ cnt, int* __restrict__ rp,
                        int* __restrict__ bsum, int n) {
    __shared__ int s[SB];
    int t = threadIdx.x;
    int i = blockIdx.x * SB + t;
    int v = (i < n) ? cnt[i] : 0;
    s[t] = v;
    __syncthreads();
    for (int off = 1; off < SB; off <<= 1) {
        int u = (t >= off) ? s[t - off] : 0;
        __syncthreads();
        s[t] += u;
        __syncthreads();
    }
    if (i < n) rp[i + 1] = s[t];
    if (t == SB - 1) bsum[blockIdx.x] = s[t];
}

// single block: exclusive scan of block sums (nb <= 1024; here nb = 391)
__global__ void k_scan2(const int* __restrict__ bsum, int* __restrict__ boff, int nb) {
    __shared__ int s[1024];
    int t = threadIdx.x;
    int v = (t < nb) ? bsum[t] : 0;
    s[t] = v;
    __syncthreads();
    for (int off = 1; off < 1024; off <<= 1) {
        int u = (t >= off) ? s[t - off] : 0;
        __syncthreads();
        s[t] += u;
        __syncthreads();
    }
    if (t < nb) boff[t] = s[t] - v;  // exclusive
}

__global__ void k_scan3(int* __restrict__ rp, const int* __restrict__ boff, int n) {
    int i = blockIdx.x * blockDim.x + threadIdx.x;
    if (i < n) {
        rp[i + 1] += boff[i / SB];
        if (i == 0) rp[0] = 0;
    }
}

__global__ void k_fill(const int* __restrict__ src, const int* __restrict__ dst,
                       const int* __restrict__ rp, int* __restrict__ cursor,
                       int* __restrict__ col, int E) {
    int e = blockIdx.x * blockDim.x + threadIdx.x;
    if (e < E) {
        int d = dst[e];
        int p = atomicAdd(&cursor[d], 1);
        col[rp[d] + p] = src[e];
    }
}

// ---------------- normalized aggregation (gather form) ----------------
// out[n][t] = dinv[n]^2 * in[n][t] + sum_{e in CSR(n)} dinv[col[e]]*dinv[n] * in[col[e]][t]
__global__ __launch_bounds__(D) void k_agg(const float* __restrict__ in,
                                           float* __restrict__ out,
                                           const int* __restrict__ col,
                                           const int* __restrict__ rp,
                                           const float* __restrict__ dinv, int n) {
    int node = blockIdx.x;
    int t = threadIdx.x;
    float dn = dinv[node];
    float acc = in[(size_t)node * D + t] * (dn * dn);  // self loop
    int e0 = rp[node], e1 = rp[node + 1];
    for (int e = e0; e < e1; ++e) {
        int s = col[e];
        float w = dinv[s] * dn;
        acc = fmaf(in[(size_t)s * D + t], w, acc);
    }
    out[(size_t)node * D + t] = acc;
}

// ---------------- GEMM + bias + relu (f32, register tiled) ----------------
// out[r][c] = relu( sum_k A[r][k] * W[k][c] + bias[c] ), A: [N,128], W: [128,128]
__global__ __launch_bounds__(256) void k_gemm_bias_relu(const float* __restrict__ A,
                                                        const float* __restrict__ W,
                                                        const float* __restrict__ bias,
                                                        float* __restrict__ out, int N) {
    __shared__ float As[8][132];  // [k][row], padded
    __shared__ float Ws[8][132];  // [k][col], padded
    int tid = threadIdx.x;
    int row0 = blockIdx.x * 128;
    int ty = tid >> 4;   // 0..15 -> rows ty*8..+8
    int tx = tid & 15;   // 0..15 -> cols {tx*4..+4, 64+tx*4..+4}

    float acc[8][8];
#pragma unroll
    for (int i = 0; i < 8; ++i)
#pragma unroll
        for (int j = 0; j < 8; ++j) acc[i][j] = 0.0f;

    int ar = tid >> 1;            // 0..127
    int ac4 = (tid & 1) * 4;      // 0 or 4
    int wk = tid >> 5;            // 0..7
    int wc4 = (tid & 31) * 4;     // 0..124

    for (int kk = 0; kk < 128; kk += 8) {
        // stage A tile: As[k][row] = A[row0+row][kk+k]
        float4 av = make_float4(0.f, 0.f, 0.f, 0.f);
        if (row0 + ar < N)
            av = *reinterpret_cast<const float4*>(&A[(size_t)(row0 + ar) * 128 + kk + ac4]);
        As[ac4 + 0][ar] = av.x;
        As[ac4 + 1][ar] = av.y;
        As[ac4 + 2][ar] = av.z;
        As[ac4 + 3][ar] = av.w;
        // stage W tile: Ws[k][c] = W[(kk+k)][c]
        float4 wv = *reinterpret_cast<const float4*>(&W[(size_t)(kk + wk) * 128 + wc4]);
        *reinterpret_cast<float4*>(&Ws[wk][wc4]) = wv;
        __syncthreads();

#pragma unroll
        for (int k = 0; k < 8; ++k) {
            float a[8], w[8];
#pragma unroll
            for (int i = 0; i < 8; ++i) a[i] = As[k][ty * 8 + i];
#pragma unroll
            for (int j = 0; j < 4; ++j) {
                w[j] = Ws[k][tx * 4 + j];
                w[4 + j] = Ws[k][64 + tx * 4 + j];
            }
#pragma unroll
            for (int i = 0; i < 8; ++i)
#pragma unroll
                for (int j = 0; j < 8; ++j) acc[i][j] = fmaf(a[i], w[j], acc[i][j]);
        }
        __syncthreads();
    }

#pragma unroll
    for (int i = 0; i < 8; ++i) {
        int r = row0 + ty * 8 + i;
        if (r < N) {
#pragma unroll
            for (int j = 0; j < 4; ++j) {
                int c0 = tx * 4 + j;
                int c1 = 64 + tx * 4 + j;
                out[(size_t)r * 128 + c0] = fmaxf(acc[i][j] + bias[c0], 0.0f);
                out[(size_t)r * 128 + c1] = fmaxf(acc[i][4 + j] + bias[c1], 0.0f);
            }
        }
    }
}

// ---------------- launch ----------------

extern "C" void kernel_launch(void* const* d_in, const int* in_sizes, int n_in,
                              void* d_out, int out_size, void* d_ws, size_t ws_size,
                              hipStream_t stream) {
    const float* x  = (const float*)d_in[0];
    const int*   ei = (const int*)d_in[1];
    const float* W1 = (const float*)d_in[2];
    const float* b1 = (const float*)d_in[3];
    const float* W2 = (const float*)d_in[4];
    const float* b2 = (const float*)d_in[5];
    float* out = (float*)d_out;

    const int N = in_sizes[0] / D;
    const int E = in_sizes[1] / 2;
    const int* src = ei;
    const int* dst = ei + E;

    char* w = (char*)d_ws;
    auto alloc = [&](size_t bytes) -> void* {
        void* p = (void*)w;
        w += (bytes + 255) & ~(size_t)255;
        return p;
    };
    float* dinv  = (float*)alloc((size_t)N * 4);
    int* cnt     = (int*)alloc((size_t)N * 4);
    int* rp      = (int*)alloc((size_t)(N + 1) * 4);
    int* cursor  = (int*)alloc((size_t)N * 4);
    int* bsum    = (int*)alloc(4096);
    int* boff    = (int*)alloc(4096);
    int* col     = (int*)alloc((size_t)E * 4);
    float* abuf  = (float*)alloc((size_t)N * D * 4);

    const int nb = (N + SB - 1) / SB;  // 391 for N=100000, fits k_scan2's 1024

    k_init<<<(N + 255) / 256, 256, 0, stream>>>(cnt, cursor, N);
    k_count<<<(E + 255) / 256, 256, 0, stream>>>(dst, cnt, E);
    k_dinv<<<(N + 255) / 256, 256, 0, stream>>>(cnt, dinv, N);
    k_scan1<<<nb, SB, 0, stream>>>(cnt, rp, bsum, N);
    k_scan2<<<1, 1024, 0, stream>>>(bsum, boff, nb);
    k_scan3<<<(N + 255) / 256, 256, 0, stream>>>(rp, boff, N);
    k_fill<<<(E + 255) / 256, 256, 0, stream>>>(src, dst, rp, cursor, col, E);

    // layer 1: aggregate(x) -> abuf, then (abuf @ W1 + b1).relu -> out
    k_agg<<<N, D, 0, stream>>>(x, abuf, col, rp, dinv, N);
    k_gemm_bias_relu<<<(N + 127) / 128, 256, 0, stream>>>(abuf, W1, b1, out, N);
    // layer 2: aggregate(out) -> abuf, then (abuf @ W2 + b2).relu -> out
    k_agg<<<N, D, 0, stream>>>(out, abuf, col, rp, dinv, N);
    k_gemm_bias_relu<<<(N + 127) / 128, 256, 0, stream>>>(abuf, W2, b2, out, N);
}

// Round 2
// 488.630 us; speedup vs baseline: 1.2707x; 1.2707x over previous
//
#include <hip/hip_runtime.h>

#define D 128
#define SB 256

__device__ __forceinline__ float bf2f(unsigned short u) {
    return __uint_as_float(((unsigned int)u) << 16);
}
__device__ __forceinline__ unsigned short f2bf(float f) {
    unsigned int u = __float_as_uint(f);
    u += 0x7fffu + ((u >> 16) & 1u);  // round-to-nearest-even
    return (unsigned short)(u >> 16);
}

// ---------------- CSR build ----------------

__global__ void k_init(int* __restrict__ cnt, int* __restrict__ cursor, int n) {
    int i = blockIdx.x * blockDim.x + threadIdx.x;
    if (i < n) { cnt[i] = 0; cursor[i] = 0; }
}

__global__ void k_count(const int* __restrict__ dst, int* __restrict__ cnt, int E) {
    int e = blockIdx.x * blockDim.x + threadIdx.x;
    if (e < E) atomicAdd(&cnt[dst[e]], 1);
}

__global__ void k_dinv(const int* __restrict__ cnt, float* __restrict__ dinv, int n) {
    int i = blockIdx.x * blockDim.x + threadIdx.x;
    if (i < n) dinv[i] = rsqrtf((float)cnt[i] + 1.0f);  // +1 self-loop; deg >= 1 always
}

// inclusive scan within 256-blocks; rp[i+1] = local inclusive, bsum[b] = block total
__global__ void k_scan1(const int* __restrict__ cnt, int* __restrict__ rp,
                        int* __restrict__ bsum, int n) {
    __shared__ int s[SB];
    int t = threadIdx.x;
    int i = blockIdx.x * SB + t;
    int v = (i < n) ? cnt[i] : 0;
    s[t] = v;
    __syncthreads();
    for (int off = 1; off < SB; off <<= 1) {
        int u = (t >= off) ? s[t - off] : 0;
        __syncthreads();
        s[t] += u;
        __syncthreads();
    }
    if (i < n) rp[i + 1] = s[t];
    if (t == SB - 1) bsum[blockIdx.x] = s[t];
}

__global__ void k_scan2(const int* __restrict__ bsum, int* __restrict__ boff, int nb) {
    __shared__ int s[1024];
    int t = threadIdx.x;
    int v = (t < nb) ? bsum[t] : 0;
    s[t] = v;
    __syncthreads();
    for (int off = 1; off < 1024; off <<= 1) {
        int u = (t >= off) ? s[t - off] : 0;
        __syncthreads();
        s[t] += u;
        __syncthreads();
    }
    if (t < nb) boff[t] = s[t] - v;  // exclusive
}

__global__ void k_scan3(int* __restrict__ rp, const int* __restrict__ boff, int n) {
    int i = blockIdx.x * blockDim.x + threadIdx.x;
    if (i < n) {
        rp[i + 1] += boff[i / SB];
        if (i == 0) rp[0] = 0;
    }
}

__global__ void k_fill(const int* __restrict__ src, const int* __restrict__ dst,
                       const int* __restrict__ rp, int* __restrict__ cursor,
                       int* __restrict__ col, int E) {
    int e = blockIdx.x * blockDim.x + threadIdx.x;
    if (e < E) {
        int d = dst[e];
        int p = atomicAdd(&cursor[d], 1);
        col[rp[d] + p] = src[e];
    }
}

// ---------------- x -> bf16, pre-scaled by dinv[row] ----------------
// y[r][f] = bf16(dinv[r] * x[r][f]); thread handles 4 consecutive floats.
__global__ __launch_bounds__(256) void k_cvt(const float* __restrict__ x,
                                             const float* __restrict__ dinv,
                                             unsigned short* __restrict__ y, int nchunk) {
    int g = blockIdx.x * blockDim.x + threadIdx.x;
    if (g >= nchunk) return;
    int row = g >> 5;  // 32 chunks of 4 per 128-wide row
    float s = dinv[row];
    float4 v = reinterpret_cast<const float4*>(x)[g];
    ushort4 o;
    o.x = f2bf(v.x * s);
    o.y = f2bf(v.y * s);
    o.z = f2bf(v.z * s);
    o.w = f2bf(v.w * s);
    reinterpret_cast<ushort4*>(y)[g] = o;
}

// ---------------- normalized aggregation (gather, bf16 rows) ----------------
// out[n][f] = dinv[n] * ( y[n][f] + sum_{e in CSR(n)} y[col[e]][f] )
// 32 lanes per node, each lane owns 4 features (one ushort4 = 8B load per edge).
__global__ __launch_bounds__(256) void k_agg(const unsigned short* __restrict__ y,
                                             float* __restrict__ out,
                                             const int* __restrict__ col,
                                             const int* __restrict__ rp,
                                             const float* __restrict__ dinv, int n) {
    int node = blockIdx.x * 8 + (threadIdx.x >> 5);
    if (node >= n) return;
    int c = threadIdx.x & 31;  // feature chunk: features [4c, 4c+4)
    const ushort4* yv = reinterpret_cast<const ushort4*>(y);

    // self loop
    ushort4 v = yv[(size_t)node * 32 + c];
    float a0 = bf2f(v.x), a1 = bf2f(v.y), a2 = bf2f(v.z), a3 = bf2f(v.w);

    int e0 = rp[node], e1 = rp[node + 1];
    for (int e = e0; e < e1; ++e) {
        int s = col[e];
        ushort4 u = yv[(size_t)s * 32 + c];
        a0 += bf2f(u.x);
        a1 += bf2f(u.y);
        a2 += bf2f(u.z);
        a3 += bf2f(u.w);
    }
    float dn = dinv[node];
    float4 o = make_float4(a0 * dn, a1 * dn, a2 * dn, a3 * dn);
    reinterpret_cast<float4*>(out)[(size_t)node * 32 + c] = o;
}

// ---------------- GEMM + bias + relu (f32, register tiled) ----------------
// STORE_BF16=1: y_bf16[r][c] = bf16(dinv[r] * relu(...)), f32 out not written.
// STORE_BF16=0: out_f32[r][c] = relu(...).
// In-place safe (A == out_f32): each block reads only its own 128 rows, and all
// A reads complete (K loop + syncthreads) before any store.
template <int STORE_BF16>
__global__ __launch_bounds__(256) void k_gemm(const float* __restrict__ A,
                                              const float* __restrict__ W,
                                              const float* __restrict__ bias,
                                              float* __restrict__ out_f32,
                                              unsigned short* __restrict__ out_bf16,
                                              const float* __restrict__ dinv, int N) {
    __shared__ float As[8][132];  // [k][row], padded
    __shared__ float Ws[8][132];  // [k][col], padded
    int tid = threadIdx.x;
    int row0 = blockIdx.x * 128;
    int ty = tid >> 4;   // 0..15 -> rows ty*8..+8
    int tx = tid & 15;   // 0..15 -> cols {tx*4..+4, 64+tx*4..+4}

    float acc[8][8];
#pragma unroll
    for (int i = 0; i < 8; ++i)
#pragma unroll
        for (int j = 0; j < 8; ++j) acc[i][j] = 0.0f;

    int ar = tid >> 1;            // 0..127
    int ac4 = (tid & 1) * 4;      // 0 or 4
    int wk = tid >> 5;            // 0..7
    int wc4 = (tid & 31) * 4;     // 0..124

    for (int kk = 0; kk < 128; kk += 8) {
        float4 av = make_float4(0.f, 0.f, 0.f, 0.f);
        if (row0 + ar < N)
            av = *reinterpret_cast<const float4*>(&A[(size_t)(row0 + ar) * 128 + kk + ac4]);
        As[ac4 + 0][ar] = av.x;
        As[ac4 + 1][ar] = av.y;
        As[ac4 + 2][ar] = av.z;
        As[ac4 + 3][ar] = av.w;
        float4 wv = *reinterpret_cast<const float4*>(&W[(size_t)(kk + wk) * 128 + wc4]);
        *reinterpret_cast<float4*>(&Ws[wk][wc4]) = wv;
        __syncthreads();

#pragma unroll
        for (int k = 0; k < 8; ++k) {
            float a[8], w[8];
#pragma unroll
            for (int i = 0; i < 8; ++i) a[i] = As[k][ty * 8 + i];
#pragma unroll
            for (int j = 0; j < 4; ++j) {
                w[j] = Ws[k][tx * 4 + j];
                w[4 + j] = Ws[k][64 + tx * 4 + j];
            }
#pragma unroll
            for (int i = 0; i < 8; ++i)
#pragma unroll
                for (int j = 0; j < 8; ++j) acc[i][j] = fmaf(a[i], w[j], acc[i][j]);
        }
        __syncthreads();
    }

#pragma unroll
    for (int i = 0; i < 8; ++i) {
        int r = row0 + ty * 8 + i;
        if (r < N) {
            if (STORE_BF16) {
                float s = dinv[r];
                ushort4 p0, p1;
                p0.x = f2bf(fmaxf(acc[i][0] + bias[tx * 4 + 0], 0.f) * s);
                p0.y = f2bf(fmaxf(acc[i][1] + bias[tx * 4 + 1], 0.f) * s);
                p0.z = f2bf(fmaxf(acc[i][2] + bias[tx * 4 + 2], 0.f) * s);
                p0.w = f2bf(fmaxf(acc[i][3] + bias[tx * 4 + 3], 0.f) * s);
                p1.x = f2bf(fmaxf(acc[i][4] + bias[64 + tx * 4 + 0], 0.f) * s);
                p1.y = f2bf(fmaxf(acc[i][5] + bias[64 + tx * 4 + 1], 0.f) * s);
                p1.z = f2bf(fmaxf(acc[i][6] + bias[64 + tx * 4 + 2], 0.f) * s);
                p1.w = f2bf(fmaxf(acc[i][7] + bias[64 + tx * 4 + 3], 0.f) * s);
                *reinterpret_cast<ushort4*>(&out_bf16[(size_t)r * 128 + tx * 4]) = p0;
                *reinterpret_cast<ushort4*>(&out_bf16[(size_t)r * 128 + 64 + tx * 4]) = p1;
            } else {
#pragma unroll
                for (int j = 0; j < 4; ++j) {
                    int c0 = tx * 4 + j;
                    int c1 = 64 + tx * 4 + j;
                    out_f32[(size_t)r * 128 + c0] = fmaxf(acc[i][j] + bias[c0], 0.0f);
                    out_f32[(size_t)r * 128 + c1] = fmaxf(acc[i][4 + j] + bias[c1], 0.0f);
                }
            }
        }
    }
}

// ---------------- launch ----------------

extern "C" void kernel_launch(void* const* d_in, const int* in_sizes, int n_in,
                              void* d_out, int out_size, void* d_ws, size_t ws_size,
                              hipStream_t stream) {
    const float* x  = (const float*)d_in[0];
    const int*   ei = (const int*)d_in[1];
    const float* W1 = (const float*)d_in[2];
    const float* b1 = (const float*)d_in[3];
    const float* W2 = (const float*)d_in[4];
    const float* b2 = (const float*)d_in[5];
    float* out = (float*)d_out;

    const int N = in_sizes[0] / D;
    const int E = in_sizes[1] / 2;
    const int* src = ei;
    const int* dst = ei + E;

    char* w = (char*)d_ws;
    auto alloc = [&](size_t bytes) -> void* {
        void* p = (void*)w;
        w += (bytes + 255) & ~(size_t)255;
        return p;
    };
    float* dinv  = (float*)alloc((size_t)N * 4);
    int* cnt     = (int*)alloc((size_t)N * 4);
    int* rp      = (int*)alloc((size_t)(N + 1) * 4);
    int* cursor  = (int*)alloc((size_t)N * 4);
    int* bsum    = (int*)alloc(4096);
    int* boff    = (int*)alloc(4096);
    int* col     = (int*)alloc((size_t)E * 4);
    unsigned short* y = (unsigned short*)alloc((size_t)N * D * 2);  // bf16 rows (shared L1/L2)

    const int nb = (N + SB - 1) / SB;  // 391 for N=100000

    k_init<<<(N + 255) / 256, 256, 0, stream>>>(cnt, cursor, N);
    k_count<<<(E + 255) / 256, 256, 0, stream>>>(dst, cnt, E);
    k_dinv<<<(N + 255) / 256, 256, 0, stream>>>(cnt, dinv, N);
    k_scan1<<<nb, SB, 0, stream>>>(cnt, rp, bsum, N);
    k_scan2<<<1, 1024, 0, stream>>>(bsum, boff, nb);
    k_scan3<<<(N + 255) / 256, 256, 0, stream>>>(rp, boff, N);
    k_fill<<<(E + 255) / 256, 256, 0, stream>>>(src, dst, rp, cursor, col, E);

    const int nchunk = N * (D / 4);
    const int aggblocks = (N + 7) / 8;

    // layer 1: y = bf16(dinv*x); a1 = agg(y) -> out; h1y = bf16(dinv*relu(a1@W1+b1)) -> y
    k_cvt<<<(nchunk + 255) / 256, 256, 0, stream>>>(x, dinv, y, nchunk);
    k_agg<<<aggblocks, 256, 0, stream>>>(y, out, col, rp, dinv, N);
    k_gemm<1><<<(N + 127) / 128, 256, 0, stream>>>(out, W1, b1, nullptr, y, dinv, N);
    // layer 2: a2 = agg(y) -> out; out = relu(a2@W2+b2) (in-place GEMM)
    k_agg<<<aggblocks, 256, 0, stream>>>(y, out, col, rp, dinv, N);
    k_gemm<0><<<(N + 127) / 128, 256, 0, stream>>>(out, W2, b2, out, nullptr, dinv, N);
}